// Round 7
// baseline (269.706 us; speedup 1.0000x reference)
//
#include <hip/hip_runtime.h>

// M[t, i*768+p, j*768+q] = A[t,i,j] * exp(-maha - 0.5*logdet(D_tij)), row-normalized.
// D is 2x2 SPD -> closed-form inverse, coef = A * det^-1/2.
//
// R11: TWO-PASS PARADIGM. Five structural variants of the single-pass kernel
// (nt stores, persistence, store-buffer splits, hoists) all landed at a ~97us
// kernel portion vs a 36us write floor. Common invariant: every store was
// gated behind a 6-deep dependent __shfl_xor butterfly + rcp (reduction on
// the store path). This version removes it:
//   K1: compute row sums only (butterfly off the store path, writes 147KB of
//       inverses to d_ws).  ~15us.
//   K2: recompute exps with inv FOLDED INTO THE COEFFICIENT -> pure
//       dependency-free streaming stores, zero cross-lane ops, low VGPR.
// Cost: 2x compute (~+10us VALU) -- cheap vs the 60us of unexplained stall.
// Fallback: proven single-pass kernel if ws_size < 147456.

typedef unsigned int u32;

namespace {
constexpr float GAMMA_C   = 0.3f;
constexpr float JITTER_C  = 1e-5f;
constexpr float ELL_MIN_C = 0.05f;
constexpr float ELL_MAX_C = 10.0f;
constexpr int   NPT     = 768;
constexpr int   TSTEPS  = 24;
constexpr int   ROWS    = TSTEPS * 2 * NPT;   // 36864
constexpr int   W_ROWS  = 4;                  // rows per wave
constexpr int   WAVES   = 4;                  // waves per block
constexpr int   THREADS = WAVES * 64;         // 256
constexpr int   RPB     = W_ROWS * WAVES;     // 16 rows per block
constexpr int   BLOCKS  = ROWS / RPB;         // 2304
}

// Shared per-(t,i) parameter computation: shifts, D^-1, coef for both jj.
__device__ __forceinline__ void load_params(
    const float* __restrict__ mu_seq, const float* __restrict__ Sg,
    const float* __restrict__ A, const float* __restrict__ rl,
    int t, int i,
    float (&shift0)[2], float (&shift1)[2],
    float (&i00)[2], float (&i01x2)[2], float (&i11)[2], float (&coef)[2])
{
    const float g = GAMMA_C;
    float mu[4];
#pragma unroll
    for (int k = 0; k < 4; ++k) mu[k] = mu_seq[t * 4 + k];
    float Sgm[4][4];
#pragma unroll
    for (int r = 0; r < 4; ++r)
#pragma unroll
        for (int c = 0; c < 4; ++c) Sgm[r][c] = Sg[t * 16 + r * 4 + c];

    const int bi = 2 * i;
#pragma unroll
    for (int jj = 0; jj < 2; ++jj) {
        const int bj = 2 * jj;
        shift0[jj] = mu[bi]     - g * mu[bj];
        shift1[jj] = mu[bi + 1] - g * mu[bj + 1];
        const float b00 = Sgm[bi][bi]     - g*Sgm[bi][bj]     - g*Sgm[bj][bi]     + g*g*Sgm[bj][bj];
        const float b01 = Sgm[bi][bi+1]   - g*Sgm[bi][bj+1]   - g*Sgm[bj][bi+1]   + g*g*Sgm[bj][bj+1];
        const float b11 = Sgm[bi+1][bi+1] - g*Sgm[bi+1][bj+1] - g*Sgm[bj+1][bi+1] + g*g*Sgm[bj+1][bj+1];
        const float rlv = rl[i * 2 + jj];
        const float ell = ELL_MIN_C + (ELL_MAX_C - ELL_MIN_C) / (1.0f + __expf(-rlv));
        const float e2  = ell * ell + JITTER_C;
        const float D00 = e2 + 2.0f * b00;
        const float D01 =      2.0f * b01;
        const float D11 = e2 + 2.0f * b11;
        const float det  = D00 * D11 - D01 * D01;       // SPD -> det > 0
        const float rdet = 1.0f / det;
        i00[jj]   =  D11 * rdet;
        i01x2[jj] = -2.0f * D01 * rdet;                 // pre-doubled cross term
        i11[jj]   =  D00 * rdet;
        coef[jj] = A[(t * 2 + i) * 2 + jj] * rsqrtf(det);
    }
}

__device__ __forceinline__ void load_spts(const float* __restrict__ S, int lane,
                                          float (&sx)[12], float (&sy)[12])
{
#pragma unroll
    for (int m = 0; m < 3; ++m) {
        const int q0 = m * 256 + lane * 4;
        const float4 a4 = *((const float4*)(S + 2 * q0));      // x0 y0 x1 y1
        const float4 b4 = *((const float4*)(S + 2 * q0 + 4));  // x2 y2 x3 y3
        sx[4*m+0] = a4.x; sy[4*m+0] = a4.y;
        sx[4*m+1] = a4.z; sy[4*m+1] = a4.w;
        sx[4*m+2] = b4.x; sy[4*m+2] = b4.y;
        sx[4*m+3] = b4.z; sy[4*m+3] = b4.w;
    }
}

// ---------------- K1: row sums -> inv in workspace ----------------
__global__ __launch_bounds__(THREADS) void vlk_sums(
    const float* __restrict__ S, const float* __restrict__ mu_seq,
    const float* __restrict__ Sg, const float* __restrict__ A,
    const float* __restrict__ rl, float* __restrict__ wsum)  // [36864]
{
    const int w    = threadIdx.x >> 6;
    const int lane = threadIdx.x & 63;

    const int base = blockIdx.x * RPB;
    const int t    = base / (2 * NPT);
    const int rem  = base - t * (2 * NPT);
    const int i    = rem / NPT;
    const int p0   = rem - i * NPT + w * W_ROWS;

    float shift0[2], shift1[2], i00[2], i01x2[2], i11[2], coef[2];
    load_params(mu_seq, Sg, A, rl, t, i, shift0, shift1, i00, i01x2, i11, coef);

    float sx[12], sy[12];
    load_spts(S, lane, sx, sy);

#pragma unroll
    for (int r = 0; r < W_ROWS; ++r) {
        const int p = p0 + r;
        const float sp0 = S[2 * p];
        const float sp1 = S[2 * p + 1];

        float lsum = 0.0f;
#pragma unroll
        for (int jj = 0; jj < 2; ++jj) {
            const float cx = sp0 - shift0[jj];
            const float cy = sp1 - shift1[jj];
            const float a0 = i00[jj], a1x2 = i01x2[jj], a2 = i11[jj], cf = coef[jj];
#pragma unroll
            for (int q = 0; q < 12; ++q) {
                const float h0 = cx - sx[q];
                const float h1 = cy - sy[q];
                const float maha = (a0 * h0 + a1x2 * h1) * h0 + a2 * h1 * h1;
                lsum += cf * __expf(-maha);
            }
        }
#pragma unroll
        for (int off = 1; off < 64; off <<= 1) lsum += __shfl_xor(lsum, off, 64);
        if (lane == 0)
            wsum[base + w * W_ROWS + r] = 1.0f / fmaxf(lsum, 1e-8f);
    }
}

// ---------------- K2: recompute + scale + pure streaming stores ----------------
__global__ __launch_bounds__(THREADS) void vlk_store(
    const float* __restrict__ S, const float* __restrict__ mu_seq,
    const float* __restrict__ Sg, const float* __restrict__ A,
    const float* __restrict__ rl, const float* __restrict__ wsum,
    float* __restrict__ out)
{
    const int w    = threadIdx.x >> 6;
    const int lane = threadIdx.x & 63;

    const int base = blockIdx.x * RPB;
    const int t    = base / (2 * NPT);
    const int rem  = base - t * (2 * NPT);
    const int i    = rem / NPT;
    const int p0   = rem - i * NPT + w * W_ROWS;

    float shift0[2], shift1[2], i00[2], i01x2[2], i11[2], coef[2];
    load_params(mu_seq, Sg, A, rl, t, i, shift0, shift1, i00, i01x2, i11, coef);

    float sx[12], sy[12];
    load_spts(S, lane, sx, sy);

#pragma unroll
    for (int r = 0; r < W_ROWS; ++r) {
        const int row = base + w * W_ROWS + r;
        const int p = p0 + r;
        const float sp0 = S[2 * p];
        const float sp1 = S[2 * p + 1];
        const float inv = wsum[row];         // uniform load -> L2 broadcast

        float* op = out + (size_t)row * (2 * NPT);
#pragma unroll
        for (int k = 0; k < 6; ++k) {        // chunk: col = k*256 + lane*4
            const int jj = (k >= 3) ? 1 : 0;
            const int m  = k - 3 * jj;
            const float cx = sp0 - shift0[jj];
            const float cy = sp1 - shift1[jj];
            const float a0 = i00[jj], a1x2 = i01x2[jj], a2 = i11[jj];
            const float cfi = coef[jj] * inv;      // sum folded into coefficient
            float4 o;
            {
                const float h0 = cx - sx[4*m+0], h1 = cy - sy[4*m+0];
                o.x = cfi * __expf(-((a0*h0 + a1x2*h1)*h0 + a2*h1*h1));
            }
            {
                const float h0 = cx - sx[4*m+1], h1 = cy - sy[4*m+1];
                o.y = cfi * __expf(-((a0*h0 + a1x2*h1)*h0 + a2*h1*h1));
            }
            {
                const float h0 = cx - sx[4*m+2], h1 = cy - sy[4*m+2];
                o.z = cfi * __expf(-((a0*h0 + a1x2*h1)*h0 + a2*h1*h1));
            }
            {
                const float h0 = cx - sx[4*m+3], h1 = cy - sy[4*m+3];
                o.w = cfi * __expf(-((a0*h0 + a1x2*h1)*h0 + a2*h1*h1));
            }
            *((float4*)(op + k * 256 + lane * 4)) = o;   // no deps: streams
        }
    }
}

// ---------------- fallback: proven single-pass (R0 structure) ----------------
__global__ __launch_bounds__(THREADS) void vlk_single(
    const float* __restrict__ S, const float* __restrict__ mu_seq,
    const float* __restrict__ Sg, const float* __restrict__ A,
    const float* __restrict__ rl, float* __restrict__ out)
{
    const int w    = threadIdx.x >> 6;
    const int lane = threadIdx.x & 63;
    const int base = blockIdx.x * RPB;
    const int t    = base / (2 * NPT);
    const int rem  = base - t * (2 * NPT);
    const int i    = rem / NPT;
    const int p0   = rem - i * NPT + w * W_ROWS;

    float shift0[2], shift1[2], i00[2], i01x2[2], i11[2], coef[2];
    load_params(mu_seq, Sg, A, rl, t, i, shift0, shift1, i00, i01x2, i11, coef);
    float sx[12], sy[12];
    load_spts(S, lane, sx, sy);

#pragma unroll
    for (int r = 0; r < W_ROWS; ++r) {
        const int p = p0 + r;
        const float sp0 = S[2 * p];
        const float sp1 = S[2 * p + 1];
        float vals[24];
        float lsum = 0.0f;
#pragma unroll
        for (int k = 0; k < 6; ++k) {
            const int jj = (k >= 3) ? 1 : 0;
            const int m  = k - 3 * jj;
            const float cx = sp0 - shift0[jj], cy = sp1 - shift1[jj];
            const float a0 = i00[jj], a1x2 = i01x2[jj], a2 = i11[jj], cf = coef[jj];
#pragma unroll
            for (int j = 0; j < 4; ++j) {
                const float h0 = cx - sx[4*m+j];
                const float h1 = cy - sy[4*m+j];
                const float v = cf * __expf(-((a0*h0 + a1x2*h1)*h0 + a2*h1*h1));
                vals[4*k+j] = v;
                lsum += v;
            }
        }
#pragma unroll
        for (int off = 1; off < 64; off <<= 1) lsum += __shfl_xor(lsum, off, 64);
        const float inv = 1.0f / fmaxf(lsum, 1e-8f);
        float* op = out + (size_t)(base + w * W_ROWS + r) * (2 * NPT);
#pragma unroll
        for (int k = 0; k < 6; ++k) {
            float4 o;
            o.x = vals[4*k+0] * inv; o.y = vals[4*k+1] * inv;
            o.z = vals[4*k+2] * inv; o.w = vals[4*k+3] * inv;
            *((float4*)(op + k * 256 + lane * 4)) = o;
        }
    }
}

extern "C" void kernel_launch(void* const* d_in, const int* in_sizes, int n_in,
                              void* d_out, int out_size, void* d_ws, size_t ws_size,
                              hipStream_t stream) {
    const float* S  = (const float*)d_in[0];
    const float* mu = (const float*)d_in[1];
    const float* Sg = (const float*)d_in[2];
    const float* A  = (const float*)d_in[3];
    const float* rl = (const float*)d_in[4];
    if (d_ws != nullptr && ws_size >= (size_t)ROWS * sizeof(float)) {
        float* wsum = (float*)d_ws;
        vlk_sums <<<BLOCKS, THREADS, 0, stream>>>(S, mu, Sg, A, rl, wsum);
        vlk_store<<<BLOCKS, THREADS, 0, stream>>>(S, mu, Sg, A, rl, wsum, (float*)d_out);
    } else {
        vlk_single<<<BLOCKS, THREADS, 0, stream>>>(S, mu, Sg, A, rl, (float*)d_out);
    }
}

// Round 8
// 230.822 us; speedup vs baseline: 1.1685x; 1.1685x over previous
//
#include <hip/hip_runtime.h>

// M[t, i*768+p, j*768+q] = A[t,i,j] * exp(-maha - 0.5*logdet(D_tij)), row-normalized.
// D is 2x2 SPD -> closed-form inverse, coef = A * det^-1/2.
// Structure: R0's proven single-pass (2304 blocks, 4 waves, 4 rows/wave,
// col = k*256 + lane*4 float4 stores, in-register butterfly row sum).
//
// R12: FACTOR THE QUADRATIC OUT OF THE INNER LOOP. R7's two-pass regression
// proved compute-only ~ 34us (= write floor), i.e. the kernel is co-dominated
// by per-element VALU (~26 cyc/elem: 7-op maha chain + quarter-rate exp +
// muls). maha(p,q) = E(q) + F(q)*cx(p) + G(q)*cy(p) + C(p):
//   E/F/G depend only on (jj, lane's q) -> built ONCE PER BLOCK (24 triples,
//   pre-scaled by -log2(e) so the exp is a raw v_exp_f32 via exp2).
//   C(p) folds into the per-row coefficient (1 extra exp2 per row per jj).
// Inner element: 2 FMA + exp2 + mul + add  (~14-16 cyc, was ~26).
// Numerics: term magnitudes <= ~30 for this data -> exponent cancellation
// error ~1e-6, negligible vs the 3e-5 absmax already carried.

typedef unsigned int u32;

namespace {
constexpr float GAMMA_C   = 0.3f;
constexpr float JITTER_C  = 1e-5f;
constexpr float ELL_MIN_C = 0.05f;
constexpr float ELL_MAX_C = 10.0f;
constexpr float L2E       = 1.4426950408889634f;   // log2(e)
constexpr int   NPT     = 768;
constexpr int   TSTEPS  = 24;
constexpr int   ROWS    = TSTEPS * 2 * NPT;   // 36864
constexpr int   W_ROWS  = 4;                  // rows per wave
constexpr int   WAVES   = 4;                  // waves per block
constexpr int   THREADS = WAVES * 64;         // 256
constexpr int   RPB     = W_ROWS * WAVES;     // 16 rows per block
constexpr int   BLOCKS  = ROWS / RPB;         // 2304
}

__device__ __forceinline__ float fast_exp2(float x) {
#if __has_builtin(__builtin_amdgcn_exp2f)
    return __builtin_amdgcn_exp2f(x);          // raw v_exp_f32
#else
    return __expf(x * 0.6931471805599453f);
#endif
}

__global__ __launch_bounds__(THREADS) void vlk_kernel(
    const float* __restrict__ S,         // [768,2]
    const float* __restrict__ mu_seq,    // [24,4]
    const float* __restrict__ Sg,        // [24,4,4]
    const float* __restrict__ A,         // [24,2,2]
    const float* __restrict__ rl,        // [2,2]
    float* __restrict__ out)             // [24,1536,1536]
{
    const int w    = threadIdx.x >> 6;
    const int lane = threadIdx.x & 63;

    const int base = blockIdx.x * RPB;          // first row of this block
    const int t    = base / (2 * NPT);
    const int rem  = base - t * (2 * NPT);
    const int i    = rem / NPT;                 // row-block index (uniform)
    const int p0   = rem - i * NPT + w * W_ROWS;

    // ---- per-(t,i) params for BOTH jj ----
    float mu[4];
#pragma unroll
    for (int k = 0; k < 4; ++k) mu[k] = mu_seq[t * 4 + k];
    float Sgm[4][4];
#pragma unroll
    for (int r = 0; r < 4; ++r)
#pragma unroll
        for (int c = 0; c < 4; ++c) Sgm[r][c] = Sg[t * 16 + r * 4 + c];

    float shift0[2], shift1[2], a0[2], a1[2], a2[2], cf[2];
    const int bi = 2 * i;
    const float g = GAMMA_C;
#pragma unroll
    for (int jj = 0; jj < 2; ++jj) {
        const int bj = 2 * jj;
        shift0[jj] = mu[bi]     - g * mu[bj];
        shift1[jj] = mu[bi + 1] - g * mu[bj + 1];
        const float b00 = Sgm[bi][bi]     - g*Sgm[bi][bj]     - g*Sgm[bj][bi]     + g*g*Sgm[bj][bj];
        const float b01 = Sgm[bi][bi+1]   - g*Sgm[bi][bj+1]   - g*Sgm[bj][bi+1]   + g*g*Sgm[bj][bj+1];
        const float b11 = Sgm[bi+1][bi+1] - g*Sgm[bi+1][bj+1] - g*Sgm[bj+1][bi+1] + g*g*Sgm[bj+1][bj+1];
        const float rlv = rl[i * 2 + jj];
        const float ell = ELL_MIN_C + (ELL_MAX_C - ELL_MIN_C) / (1.0f + __expf(-rlv));
        const float e2  = ell * ell + JITTER_C;
        const float D00 = e2 + 2.0f * b00;
        const float D01 =      2.0f * b01;
        const float D11 = e2 + 2.0f * b11;
        const float det  = D00 * D11 - D01 * D01;       // SPD -> det > 0
        const float rdet = 1.0f / det;
        a0[jj] =  D11 * rdet;
        a1[jj] = -2.0f * D01 * rdet;                    // doubled cross coeff
        a2[jj] =  D00 * rdet;
        cf[jj] = A[(t * 2 + i) * 2 + jj] * rsqrtf(det);
    }

    // ---- per-(jj, q) triples, built ONCE per block; sx/sy die here ----
    // maha = Eq + Fq*cx + Gq*cy + Cr;  exponent2 = -L2E*maha
    //   e2t = -L2E*(a0 sx^2 + a1 sx sy + a2 sy^2)
    //   f2t = +L2E*(2 a0 sx + a1 sy)        (= -L2E * d maha/d cx cross term)
    //   g2t = +L2E*(2 a2 sy + a1 sx)
    float e2t[24], f2t[24], g2t[24];
#pragma unroll
    for (int m = 0; m < 3; ++m) {
        const int q0 = m * 256 + lane * 4;
        const float4 A4 = *((const float4*)(S + 2 * q0));      // x0 y0 x1 y1
        const float4 B4 = *((const float4*)(S + 2 * q0 + 4));  // x2 y2 x3 y3
        const float px[4] = {A4.x, A4.z, B4.x, B4.z};
        const float py[4] = {A4.y, A4.w, B4.y, B4.w};
#pragma unroll
        for (int j = 0; j < 4; ++j) {
            const float sxv = px[j], syv = py[j];
#pragma unroll
            for (int jj = 0; jj < 2; ++jj) {
                const int idx = jj * 12 + m * 4 + j;
                e2t[idx] = -L2E * ((a0[jj] * sxv + a1[jj] * syv) * sxv + a2[jj] * syv * syv);
                f2t[idx] =  L2E * (2.0f * a0[jj] * sxv + a1[jj] * syv);
                g2t[idx] =  L2E * (2.0f * a2[jj] * syv + a1[jj] * sxv);
            }
        }
    }

    // ---- 4 rows per wave ----
#pragma unroll
    for (int r = 0; r < W_ROWS; ++r) {
        const int p = p0 + r;
        const float sp0 = S[2 * p];          // uniform per wave -> broadcast
        const float sp1 = S[2 * p + 1];

        // per-row: fold row-constant quadratic into the coefficient
        float cx[2], cy[2], cfr[2];
#pragma unroll
        for (int jj = 0; jj < 2; ++jj) {
            cx[jj] = sp0 - shift0[jj];
            cy[jj] = sp1 - shift1[jj];
            const float C2 = -L2E * ((a0[jj] * cx[jj] + a1[jj] * cy[jj]) * cx[jj]
                                     + a2[jj] * cy[jj] * cy[jj]);
            cfr[jj] = cf[jj] * fast_exp2(C2);
        }

        float vals[24];
        float lsum = 0.0f;
#pragma unroll
        for (int k = 0; k < 6; ++k) {        // chunk: col = k*256 + lane*4
            const int jj = (k >= 3) ? 1 : 0;
            const int mb = k - 3 * jj;
            const float cxv = cx[jj], cyv = cy[jj], cfv = cfr[jj];
#pragma unroll
            for (int j = 0; j < 4; ++j) {
                const int idx = jj * 12 + mb * 4 + j;
                const float tq = fmaf(g2t[idx], cyv, fmaf(f2t[idx], cxv, e2t[idx]));
                const float v  = cfv * fast_exp2(tq);
                vals[4*k+j] = v;
                lsum += v;
            }
        }

        // in-register wave reduction: all lanes end with the row total
#pragma unroll
        for (int off = 1; off < 64; off <<= 1) lsum += __shfl_xor(lsum, off, 64);
        const float inv = 1.0f / fmaxf(lsum, 1e-8f);    // clip(sum, 1e-8)

        float* op = out + (size_t)(base + w * W_ROWS + r) * (2 * NPT);
#pragma unroll
        for (int k = 0; k < 6; ++k) {
            float4 o;
            o.x = vals[4*k+0] * inv;
            o.y = vals[4*k+1] * inv;
            o.z = vals[4*k+2] * inv;
            o.w = vals[4*k+3] * inv;
            *((float4*)(op + k * 256 + lane * 4)) = o;
        }
    }
}

extern "C" void kernel_launch(void* const* d_in, const int* in_sizes, int n_in,
                              void* d_out, int out_size, void* d_ws, size_t ws_size,
                              hipStream_t stream) {
    vlk_kernel<<<BLOCKS, THREADS, 0, stream>>>(
        (const float*)d_in[0],   // S
        (const float*)d_in[1],   // mu_seq
        (const float*)d_in[2],   // Sigma_seq
        (const float*)d_in[3],   // A_seq
        (const float*)d_in[4],   // raw_ell
        (float*)d_out);
}